// Round 8
// baseline (916.402 us; speedup 1.0000x reference)
//
#include <hip/hip_runtime.h>
#include <hip/hip_bf16.h>
#include <cstdint>
#include <cstddef>

// B=4, L=2048, H=2048, NH=16, HD=128. Inputs/outputs fp32.
// Round 7:  XOR chunk swizzle on flash Qs/Ks/Vt — flash 612 -> ~370 us. CONFIRMED.
// Round 9:  bf16-pre-convert x; gemm_qkv ASYNC16 both operands. 527 -> 426 us.
// Round 10: WqkvT d-fast permute + LDS-restaged V epilogue. total -> 863. CONFIRMED.
// Round 12: flash Q-in-regs + T14 reg-staged K/V prefetch. 362 -> 344.
// Round 13: DPP-butterfly softmax (no LDS shuffles). 344 -> 315. Per-wave critical
//           path ~1900 cyc with only ~740 cyc issue -> latency-bound per wave.
// Round 14: QBLK=128 per block (32 q-rows/wave as 2 row-groups). Every K/V tile,
//           ds_read B-fragment, staging barrier now serves 2x MFMA work; wave-iters
//           halve. B-frags (Ks/Vt reads) hoisted + reused across row-groups.
//           Row-group g: full if jt<2it+g, diag if ==, skipped if > (uniform).
//           VGPR ~96->~200 (2 waves/SIMD) — deliberate occupancy-for-intensity
//           trade (round 12 showed occupancy alone doesn't pay). Grid 16x64.
// Workspace exactly 128 MB; x_bf16 parked in d_out.

typedef __attribute__((ext_vector_type(4))) float f32x4;
typedef __attribute__((ext_vector_type(8))) short bf16x8;
typedef __hip_bfloat16 bf16;

#define ASYNC16(lds, g)                                                                  \
  __builtin_amdgcn_global_load_lds((const __attribute__((address_space(1))) void*)(g),   \
                                   (__attribute__((address_space(3))) void*)(lds), 16, 0, 0)

__device__ __forceinline__ float b2f(bf16 v) { return __bfloat162float(v); }
__device__ __forceinline__ bf16 f2b(float v) { return __float2bfloat16(v); }
__device__ __forceinline__ short f2bs(float f) {
  bf16 h = __float2bfloat16(f);
  return __builtin_bit_cast(short, h);
}
__device__ __forceinline__ bf16x8 pack8(f32x4 a, f32x4 b) {
  bf16x8 r;
#pragma unroll
  for (int t = 0; t < 4; ++t) r[t] = f2bs(a[t]);
#pragma unroll
  for (int t = 0; t < 4; ++t) r[4 + t] = f2bs(b[t]);
  return r;
}

// DPP butterfly steps for a 16-lane reduce (VALU-only, no LDS):
// 0xB1 = quad_perm(1,0,3,2) [xor1], 0x4E = quad_perm(2,3,0,1) [xor2],
// 0x141 = row_half_mirror [quad<->quad], 0x140 = row_mirror [8<->8].
template <int CTRL>
__device__ __forceinline__ float dpp_bfly_max(float x) {
  int xi = __builtin_bit_cast(int, x);
  int yi = __builtin_amdgcn_update_dpp(xi, xi, CTRL, 0xF, 0xF, false);
  return fmaxf(x, __builtin_bit_cast(float, yi));
}
template <int CTRL>
__device__ __forceinline__ float dpp_bfly_add(float x) {
  int xi = __builtin_bit_cast(int, x);
  int yi = __builtin_amdgcn_update_dpp(xi, xi, CTRL, 0xF, 0xF, false);
  return x + __builtin_bit_cast(float, yi);
}

// ---------------------------------------------------------------------------
// Elementwise fp32 -> bf16, 8 elems/thread, fully coalesced.
__global__ void conv_bf16(const float* __restrict__ src, bf16* __restrict__ dst) {
  size_t i = ((size_t)blockIdx.x * 256 + threadIdx.x) * 8;
  f32x4 a0 = *(const f32x4*)(src + i);
  f32x4 a1 = *(const f32x4*)(src + i + 4);
  *(bf16x8*)(dst + i) = pack8(a0, a1);
}

// ---------------------------------------------------------------------------
// Transpose+convert fp32 (R x C) -> bf16 (C x R). perm=1: qkv column remap
// col = which*2048 + d*16 + h  ->  which*2048 + h*128 + d  (dst-row permute).
__global__ void transpose_conv(const float* __restrict__ src, bf16* __restrict__ dst,
                               int R, int C, int perm) {
  __shared__ float tile[32][33];
  int bx = blockIdx.x * 32, by = blockIdx.y * 32;
  int tx = threadIdx.x, ty = threadIdx.y;
  for (int i = ty; i < 32; i += 8) tile[i][tx] = src[(size_t)(by + i) * C + bx + tx];
  __syncthreads();
  for (int i = ty; i < 32; i += 8) {
    int c = bx + i;
    if (perm) {
      int cc = c & 2047;
      c = (c & ~2047) | (((cc & 15) << 7) | (cc >> 4));
    }
    dst[(size_t)c * R + by + tx] = f2b(tile[tx][i]);
  }
}

// ---------------------------------------------------------------------------
// QKV GEMM: C(8192,6144) = xb(8192,2048) * WqkvT(6144,2048)^T. 128x128, BK=64.
// Columns permuted (d-fast). Per n-tile: one (which,h), full d in [0,128).
__global__ __launch_bounds__(256) void gemm_qkv(const bf16* __restrict__ A,
                                                const bf16* __restrict__ Bt,
                                                const float* __restrict__ biasf,
                                                bf16* __restrict__ Qg, bf16* __restrict__ Kg,
                                                bf16* __restrict__ Vg) {
  __shared__ alignas(16) bf16 smem[2 * 128 * 64];  // As | Bs; reused as [128][128] for V restage
  bf16* As = smem;
  bf16* Bs = smem + 128 * 64;
  const int K_ = 2048;
  int tid = threadIdx.x, lane = tid & 63, w = tid >> 6;
  int lr = lane & 15, hi = lane >> 4;
  int wm = (w >> 1) * 64, wn = (w & 1) * 64;
  int m0 = blockIdx.y * 128, n0 = blockIdx.x * 128;
  f32x4 acc[4][4];
#pragma unroll
  for (int im = 0; im < 4; ++im)
#pragma unroll
    for (int in = 0; in < 4; ++in) acc[im][in] = (f32x4){0.f, 0.f, 0.f, 0.f};

  for (int k0 = 0; k0 < K_; k0 += 64) {
    __syncthreads();
#pragma unroll
    for (int i = 0; i < 4; ++i) {
      int c = tid + 256 * i;
      int r = c >> 3, j = c & 7, jg = j ^ (r & 7);
      ASYNC16((char*)As + c * 16, (const char*)(A + (size_t)(m0 + r) * K_ + k0 + jg * 8));
    }
#pragma unroll
    for (int i = 0; i < 4; ++i) {
      int c = tid + 256 * i;
      int r = c >> 3, j = c & 7, jg = j ^ (r & 7);
      ASYNC16((char*)Bs + c * 16, (const char*)(Bt + (size_t)(n0 + r) * K_ + k0 + jg * 8));
    }
    __syncthreads();

#pragma unroll
    for (int ks = 0; ks < 2; ++ks) {
      bf16x8 afr[4], bfr[4];
#pragma unroll
      for (int im = 0; im < 4; ++im) {
        int r = wm + 16 * im + lr;
        afr[im] = *(const bf16x8*)((const char*)As + r * 128 + (((ks * 4 + hi) ^ (r & 7)) * 16));
      }
#pragma unroll
      for (int in = 0; in < 4; ++in) {
        int r = wn + 16 * in + lr;
        bfr[in] = *(const bf16x8*)((const char*)Bs + r * 128 + (((ks * 4 + hi) ^ (r & 7)) * 16));
      }
#pragma unroll
      for (int im = 0; im < 4; ++im)
#pragma unroll
        for (int in = 0; in < 4; ++in)
          acc[im][in] =
              __builtin_amdgcn_mfma_f32_16x16x32_bf16(afr[im], bfr[in], acc[im][in], 0, 0, 0);
    }
  }

  // Epilogue. Block-uniform: which, h. d = wn + 16*in + lr (full [0,128) per tile).
  int which = n0 >> 11;
  int h = (n0 >> 7) & 15;
  int bq = m0 >> 11;
  int l_base = m0 & 2047;
  int bh = bq * 16 + h;
  float bv[4];
#pragma unroll
  for (int in = 0; in < 4; ++in)
    bv[in] = biasf[(which << 11) + ((wn + 16 * in + lr) << 4) + h];

  if (which < 2) {
    bf16* __restrict__ G = (which == 0) ? Qg : Kg;
#pragma unroll
    for (int im = 0; im < 4; ++im) {
#pragma unroll
      for (int in = 0; in < 4; ++in) {
        int d = wn + 16 * in + lr;
#pragma unroll
        for (int j = 0; j < 4; ++j) {
          int l = l_base + wm + 16 * im + 4 * hi + j;
          G[((size_t)bh * 2048 + l) * 128 + d] = f2b(acc[im][in][j] + bv[in]);
        }
      }
    }
  } else {
    // V: restage [128 d][128 l] through LDS (XOR'd 8-elem l-chunks), 16B stores.
    __syncthreads();
#pragma unroll
    for (int im = 0; im < 4; ++im)
#pragma unroll
      for (int in = 0; in < 4; ++in) {
        int d = wn + 16 * in + lr;
#pragma unroll
        for (int j = 0; j < 4; ++j) {
          int l = wm + 16 * im + 4 * hi + j;
          int slot = (l >> 3) ^ (d & 15);
          smem[d * 128 + slot * 8 + (l & 7)] = f2b(acc[im][in][j] + bv[in]);
        }
      }
    __syncthreads();
#pragma unroll
    for (int s = 0; s < 8; ++s) {
      int d = (tid >> 4) + 16 * s;
      int lc = tid & 15;
      int slot = lc ^ (d & 15);
      bf16x8 v = *(const bf16x8*)(smem + d * 128 + slot * 8);
      *(bf16x8*)(Vg + ((size_t)bh * 128 + d) * 2048 + l_base + lc * 8) = v;
    }
  }
}

// ---------------------------------------------------------------------------
// FC2 GEMM: Out(8192,2048) = Y(8192,2048) * Wfc2T(2048,2048)^T, bias+SiLU, fp32 out.
__global__ __launch_bounds__(256) void gemm_fc2(const bf16* __restrict__ A,
                                                const bf16* __restrict__ Bt,
                                                const float* __restrict__ biasf,
                                                float* __restrict__ Out) {
  __shared__ alignas(16) bf16 As[128 * 64];
  __shared__ alignas(16) bf16 Bs[128 * 64];
  const int K_ = 2048;
  int tid = threadIdx.x, lane = tid & 63, w = tid >> 6;
  int lr = lane & 15, hi = lane >> 4;
  int wm = (w >> 1) * 64, wn = (w & 1) * 64;
  int m0 = blockIdx.y * 128, n0 = blockIdx.x * 128;
  f32x4 acc[4][4];
#pragma unroll
  for (int im = 0; im < 4; ++im)
#pragma unroll
    for (int in = 0; in < 4; ++in) acc[im][in] = (f32x4){0.f, 0.f, 0.f, 0.f};

  for (int k0 = 0; k0 < K_; k0 += 64) {
    __syncthreads();
#pragma unroll
    for (int i = 0; i < 4; ++i) {
      int c = tid + 256 * i;
      int r = c >> 3, j = c & 7, jg = j ^ (r & 7);
      ASYNC16((char*)As + c * 16, (const char*)(A + (size_t)(m0 + r) * K_ + k0 + jg * 8));
    }
#pragma unroll
    for (int i = 0; i < 4; ++i) {
      int c = tid + 256 * i;
      int r = c >> 3, j = c & 7, jg = j ^ (r & 7);
      ASYNC16((char*)Bs + c * 16, (const char*)(Bt + (size_t)(n0 + r) * K_ + k0 + jg * 8));
    }
    __syncthreads();
#pragma unroll
    for (int ks = 0; ks < 2; ++ks) {
      bf16x8 afr[4], bfr[4];
#pragma unroll
      for (int im = 0; im < 4; ++im) {
        int r = wm + 16 * im + lr;
        afr[im] = *(const bf16x8*)((const char*)As + r * 128 + (((ks * 4 + hi) ^ (r & 7)) * 16));
      }
#pragma unroll
      for (int in = 0; in < 4; ++in) {
        int r = wn + 16 * in + lr;
        bfr[in] = *(const bf16x8*)((const char*)Bs + r * 128 + (((ks * 4 + hi) ^ (r & 7)) * 16));
      }
#pragma unroll
      for (int im = 0; im < 4; ++im)
#pragma unroll
        for (int in = 0; in < 4; ++in)
          acc[im][in] =
              __builtin_amdgcn_mfma_f32_16x16x32_bf16(afr[im], bfr[in], acc[im][in], 0, 0, 0);
    }
  }

#pragma unroll
  for (int im = 0; im < 4; ++im) {
#pragma unroll
    for (int in = 0; in < 4; ++in) {
      int c = n0 + wn + 16 * in + lr;
      float bv = biasf[c];
#pragma unroll
      for (int j = 0; j < 4; ++j) {
        int m = m0 + wm + 16 * im + 4 * hi + j;
        float z = acc[im][in][j] + bv;
        Out[(size_t)m * 2048 + c] = z / (1.f + __expf(-z));
      }
    }
  }
}

// ---------------------------------------------------------------------------
// Rotary in-place on Q,K head layout. Pair (d, d+64), angle col = d*16+h. fp32 cos/sin.
__global__ void rotary_kernel(bf16* __restrict__ Qg, bf16* __restrict__ Kg,
                              const float* __restrict__ cosp, const float* __restrict__ sinp) {
  int idx = blockIdx.x * 256 + threadIdx.x;  // B*NH*L*64 = 8388608
  int d = idx & 63;
  int l = (idx >> 6) & 2047;
  int bh = idx >> 17;
  int h = bh & 15;
  size_t base = ((size_t)bh * 2048 + l) * 128;
  int ang = l * 1024 + d * 16 + h;
  float c = cosp[ang], s = sinp[ang];
  float q1 = b2f(Qg[base + d]), q2 = b2f(Qg[base + d + 64]);
  Qg[base + d] = f2b(q1 * c + q2 * s);
  Qg[base + d + 64] = f2b(-q1 * s + q2 * c);
  float k1 = b2f(Kg[base + d]), k2 = b2f(Kg[base + d + 64]);
  Kg[base + d] = f2b(k1 * c + k2 * s);
  Kg[base + d + 64] = f2b(-k1 * s + k2 * c);
}

// ---------------------------------------------------------------------------
// Causal flash attention. Round 14: QBLK=128, 32 q-rows/wave (2 row-groups).
// K/V tiles + B-fragments reused across row-groups; per-work staging halves.
__global__ __launch_bounds__(256) void flash_kernel(const bf16* __restrict__ Qg,
                                                    const bf16* __restrict__ Kg,
                                                    const bf16* __restrict__ Vg,
                                                    bf16* __restrict__ Y) {
  __shared__ alignas(16) bf16 Ks[64 * 128];
  __shared__ alignas(16) bf16 Vt[128 * 64];
  __shared__ alignas(16) bf16 Ps[4 * 32 * 72];  // 18 KB, wave-private regions
  int tid = threadIdx.x, lane = tid & 63, w = tid >> 6;
  int lr = lane & 15, hi = lane >> 4;
  int it = 15 - (int)blockIdx.x;
  int bh = blockIdx.y;
  int b = bh >> 4, h = bh & 15;
  int q0 = it * 128;
  const bf16* Qb = Qg + (size_t)bh * 2048 * 128;
  const bf16* Kb = Kg + (size_t)bh * 2048 * 128;
  const bf16* Vb = Vg + (size_t)bh * 128 * 2048;
  const float NEG = -1.0e30f;
  int ar = 16 * w + lr;

  // Q fragments for both row-groups straight to registers.
  bf16x8 qf[2][4];
#pragma unroll
  for (int g = 0; g < 2; ++g)
#pragma unroll
    for (int ks = 0; ks < 4; ++ks)
      qf[g][ks] = *(const bf16x8*)(Qb + (size_t)(q0 + 64 * g + ar) * 128 + (ks * 4 + hi) * 8);

  // Prologue: issue K/V loads for jt=0 into staging registers.
  bf16x8 kreg[4], vreg[4];
#pragma unroll
  for (int i = 0; i < 4; ++i) {
    int c = tid + 256 * i;
    int rk = c >> 4, jk = (c & 15) ^ (rk & 7);
    kreg[i] = *(const bf16x8*)(Kb + (size_t)rk * 128 + jk * 8);
    int rv = c >> 3, jv = (c & 7) ^ (rv & 7);
    vreg[i] = *(const bf16x8*)(Vb + (size_t)rv * 2048 + jv * 8);
  }

  f32x4 o[2][8];
#pragma unroll
  for (int g = 0; g < 2; ++g)
#pragma unroll
    for (int i = 0; i < 8; ++i) o[g][i] = (f32x4){0.f, 0.f, 0.f, 0.f};
  float m_i[2][4], l_i[2][4];
#pragma unroll
  for (int g = 0; g < 2; ++g)
#pragma unroll
    for (int j = 0; j < 4; ++j) { m_i[g][j] = NEG; l_i[g][j] = 0.f; }
  const float scale = 0.08838834764831845f;  // 1/sqrt(128)

  int jt_max = 2 * it + 1;
  for (int jt = 0; jt <= jt_max; ++jt) {
    __syncthreads();  // all waves done reading Ks/Vt of previous tile
#pragma unroll
    for (int i = 0; i < 4; ++i) {
      int c = tid + 256 * i;
      *(bf16x8*)((char*)Ks + c * 16) = kreg[i];
      *(bf16x8*)((char*)Vt + c * 16) = vreg[i];
    }
    __syncthreads();  // staged tile visible to all waves

    // T14: issue next tile's global loads now; consumed at next iter's ds_write.
    if (jt < jt_max) {
      int k0n = (jt + 1) * 64;
#pragma unroll
      for (int i = 0; i < 4; ++i) {
        int c = tid + 256 * i;
        int rk = c >> 4, jk = (c & 15) ^ (rk & 7);
        kreg[i] = *(const bf16x8*)(Kb + (size_t)(k0n + rk) * 128 + jk * 8);
        int rv = c >> 3, jv = (c & 7) ^ (rv & 7);
        vreg[i] = *(const bf16x8*)(Vb + (size_t)rv * 2048 + k0n + jv * 8);
      }
    }

    // QK^T: B-fragments read once, reused by both row-groups (block-uniform guards).
    f32x4 sacc[2][4];
#pragma unroll
    for (int g = 0; g < 2; ++g)
#pragma unroll
      for (int in = 0; in < 4; ++in) sacc[g][in] = (f32x4){0.f, 0.f, 0.f, 0.f};
#pragma unroll
    for (int ks = 0; ks < 4; ++ks) {
#pragma unroll
      for (int in = 0; in < 4; ++in) {
        int br = 16 * in + lr;
        bf16x8 bb =
            *(const bf16x8*)((const char*)Ks + br * 256 + (((ks * 4 + hi) ^ (br & 7)) * 16));
        if (jt <= 2 * it)
          sacc[0][in] = __builtin_amdgcn_mfma_f32_16x16x32_bf16(qf[0][ks], bb, sacc[0][in], 0, 0, 0);
        sacc[1][in] = __builtin_amdgcn_mfma_f32_16x16x32_bf16(qf[1][ks], bb, sacc[1][in], 0, 0, 0);
      }
    }

    // Softmax per row-group (g active iff jt <= 2it+g; g=1 always active here).
#pragma unroll
    for (int g = 0; g < 2; ++g) {
      if (jt > 2 * it + g) continue;  // block-uniform
      bool diag = (jt == 2 * it + g);
      float mxr[4], alpha[4], rsum[4];
#pragma unroll
      for (int j = 0; j < 4; ++j) {
        float mx = NEG;
#pragma unroll
        for (int in = 0; in < 4; ++in) {
          float s = sacc[g][in][j] * scale;
          if (diag) {
            int qg_ = 16 * w + 4 * hi + j;
            int kg_ = 16 * in + lr;
            if (kg_ > qg_) s = NEG;
          }
          sacc[g][in][j] = s;
          mx = fmaxf(mx, s);
        }
        mxr[j] = mx;
      }
#pragma unroll
      for (int j = 0; j < 4; ++j) mxr[j] = dpp_bfly_max<0xB1>(mxr[j]);
#pragma unroll
      for (int j = 0; j < 4; ++j) mxr[j] = dpp_bfly_max<0x4E>(mxr[j]);
#pragma unroll
      for (int j = 0; j < 4; ++j) mxr[j] = dpp_bfly_max<0x141>(mxr[j]);
#pragma unroll
      for (int j = 0; j < 4; ++j) mxr[j] = dpp_bfly_max<0x140>(mxr[j]);

#pragma unroll
      for (int j = 0; j < 4; ++j) {
        float mnew = fmaxf(m_i[g][j], mxr[j]);
        alpha[j] = __expf(m_i[g][j] - mnew);
        m_i[g][j] = mnew;
        float r = 0.f;
#pragma unroll
        for (int in = 0; in < 4; ++in) {
          float p = __expf(sacc[g][in][j] - mnew);
          sacc[g][in][j] = p;
          r += p;
        }
        rsum[j] = r;
      }
#pragma unroll
      for (int j = 0; j < 4; ++j) rsum[j] = dpp_bfly_add<0xB1>(rsum[j]);
#pragma unroll
      for (int j = 0; j < 4; ++j) rsum[j] = dpp_bfly_add<0x4E>(rsum[j]);
#pragma unroll
      for (int j = 0; j < 4; ++j) rsum[j] = dpp_bfly_add<0x141>(rsum[j]);
#pragma unroll
      for (int j = 0; j < 4; ++j) rsum[j] = dpp_bfly_add<0x140>(rsum[j]);

#pragma unroll
      for (int j = 0; j < 4; ++j) {
        l_i[g][j] = alpha[j] * l_i[g][j] + rsum[j];
#pragma unroll
        for (int inp = 0; inp < 8; ++inp) o[g][inp][j] *= alpha[j];
      }

#pragma unroll
      for (int j = 0; j < 4; ++j)
#pragma unroll
        for (int in = 0; in < 4; ++in)
          Ps[w * 2304 + (g * 16 + 4 * hi + j) * 72 + 16 * in + lr] = f2b(sacc[g][in][j]);
    }
    // Ps region is wave-private (w-indexed); only need this wave's LDS ops done.
    asm volatile("s_waitcnt lgkmcnt(0)" ::: "memory");

    // PV: Vt B-fragments read once, reused by both row-groups.
#pragma unroll
    for (int ko = 0; ko < 2; ++ko) {
      bf16x8 a0, a1;
      if (jt <= 2 * it)
        a0 = *(const bf16x8*)((const char*)Ps + (w * 2304 + lr * 72 + ko * 32 + hi * 8) * 2);
      a1 = *(const bf16x8*)((const char*)Ps + (w * 2304 + (16 + lr) * 72 + ko * 32 + hi * 8) * 2);
#pragma unroll
      for (int inp = 0; inp < 8; ++inp) {
        int br = 16 * inp + lr;
        bf16x8 bb =
            *(const bf16x8*)((const char*)Vt + br * 128 + (((ko * 4 + hi) ^ (br & 7)) * 16));
        if (jt <= 2 * it)
          o[0][inp] = __builtin_amdgcn_mfma_f32_16x16x32_bf16(a0, bb, o[0][inp], 0, 0, 0);
        o[1][inp] = __builtin_amdgcn_mfma_f32_16x16x32_bf16(a1, bb, o[1][inp], 0, 0, 0);
      }
    }
  }

#pragma unroll
  for (int g = 0; g < 2; ++g)
#pragma unroll
    for (int j = 0; j < 4; ++j) {
      int qg_ = q0 + 64 * g + 16 * w + 4 * hi + j;
      float inv = 1.f / l_i[g][j];
      size_t rowb = ((size_t)(b * 2048 + qg_)) * 2048 + h * 128;
#pragma unroll
      for (int inp = 0; inp < 8; ++inp) {
        int dd = 16 * inp + lr;
        Y[rowb + dd] = f2b(o[g][inp][j] * inv);
      }
    }
}

// ---------------------------------------------------------------------------
extern "C" void kernel_launch(void* const* d_in, const int* in_sizes, int n_in,
                              void* d_out, int out_size, void* d_ws, size_t ws_size,
                              hipStream_t stream) {
  const float* x    = (const float*)d_in[0];  // 8192 x 2048
  const float* Wqkv = (const float*)d_in[1];  // 2048 x 6144
  const float* bqkv = (const float*)d_in[2];  // 6144
  const float* Wfc2 = (const float*)d_in[3];  // 2048 x 2048
  const float* bfc2 = (const float*)d_in[4];  // 2048
  const float* cosp = (const float*)d_in[5];  // 2048 x 1024
  const float* sinp = (const float*)d_in[6];  // 2048 x 1024
  float* out = (float*)d_out;

  // Workspace (bf16 elems), exactly 67,108,864 = 128 MB:
  //   [0, 16.78M):      Yg (flash out). WqkvT [0,12.58M) aliased pre-flash.
  //   [16.78M, 33.55M): Qg. Wfc2T [+0,+4.19M) aliased post-flash.
  //   [33.55M, 50.33M): Kg.
  //   [50.33M, 67.11M): Vg [bh][128][l].
  // x_bf16 (16.78M elems = 33.5 MB) parked in d_out (67 MB fp32, dead until fc2).
  bf16* ws = (bf16*)d_ws;
  bf16* Yg    = ws;
  bf16* WqkvT = ws;
  bf16* Qg    = ws + 16777216;
  bf16* Wfc2T = ws + 16777216;
  bf16* Kg    = ws + 33554432;
  bf16* Vg    = ws + 50331648;
  bf16* xb    = (bf16*)d_out;

  conv_bf16<<<8192, 256, 0, stream>>>(x, xb);
  transpose_conv<<<dim3(192, 64), dim3(32, 8), 0, stream>>>(Wqkv, WqkvT, 2048, 6144, 1);
  gemm_qkv<<<dim3(48, 64), 256, 0, stream>>>(xb, WqkvT, bqkv, Qg, Kg, Vg);
  rotary_kernel<<<32768, 256, 0, stream>>>(Qg, Kg, cosp, sinp);
  flash_kernel<<<dim3(16, 64), 256, 0, stream>>>(Qg, Kg, Vg, Yg);
  transpose_conv<<<dim3(64, 64), dim3(32, 8), 0, stream>>>(Wfc2, Wfc2T, 2048, 2048, 0);
  gemm_fc2<<<dim3(16, 64), 256, 0, stream>>>(Yg, Wfc2T, bfc2, out);
}

// Round 9
// 801.288 us; speedup vs baseline: 1.1437x; 1.1437x over previous
//
#include <hip/hip_runtime.h>
#include <hip/hip_bf16.h>
#include <cstdint>
#include <cstddef>

// B=4, L=2048, H=2048, NH=16, HD=128. Inputs/outputs fp32.
// Round 7:  XOR chunk swizzle on flash Qs/Ks/Vt — flash 612 -> ~370 us. CONFIRMED.
// Round 9:  bf16-pre-convert x; gemm_qkv ASYNC16 both operands. 527 -> 426 us.
// Round 10: WqkvT d-fast permute + LDS-restaged V epilogue. total -> 863. CONFIRMED.
// Round 12: flash Q-in-regs + T14 reg-staged K/V prefetch. 362 -> 344.
// Round 13: DPP-butterfly softmax (no LDS shuffles). 344 -> 315.
// Round 14: FAILED (falsifier fired): 2 row-groups/wave lengthened the per-wave
//           chain 40% while occupancy fell 33% -> 407 us. Reverted.
// Round 15: QBLK=128 the other way: 512 threads / 8 waves, 16 q-rows per wave
//           (round-13 per-wave shape, ~96-110 VGPR). One K/V staging serves 8
//           waves; LDS 51200 -> 3 blocks/CU = 24 waves/CU = 6 waves/SIMD (2x
//           round-13 TLP, same chain). Per-wave uniform causal skip; elementwise
//           mask only on the <=2 boundary tiles. Block-iters 33792 -> 17408.
// Workspace exactly 128 MB; x_bf16 parked in d_out.

typedef __attribute__((ext_vector_type(4))) float f32x4;
typedef __attribute__((ext_vector_type(8))) short bf16x8;
typedef __hip_bfloat16 bf16;

#define ASYNC16(lds, g)                                                                  \
  __builtin_amdgcn_global_load_lds((const __attribute__((address_space(1))) void*)(g),   \
                                   (__attribute__((address_space(3))) void*)(lds), 16, 0, 0)

__device__ __forceinline__ float b2f(bf16 v) { return __bfloat162float(v); }
__device__ __forceinline__ bf16 f2b(float v) { return __float2bfloat16(v); }
__device__ __forceinline__ short f2bs(float f) {
  bf16 h = __float2bfloat16(f);
  return __builtin_bit_cast(short, h);
}
__device__ __forceinline__ bf16x8 pack8(f32x4 a, f32x4 b) {
  bf16x8 r;
#pragma unroll
  for (int t = 0; t < 4; ++t) r[t] = f2bs(a[t]);
#pragma unroll
  for (int t = 0; t < 4; ++t) r[4 + t] = f2bs(b[t]);
  return r;
}

// DPP butterfly steps for a 16-lane reduce (VALU-only, no LDS):
// 0xB1 = quad_perm(1,0,3,2) [xor1], 0x4E = quad_perm(2,3,0,1) [xor2],
// 0x141 = row_half_mirror [quad<->quad], 0x140 = row_mirror [8<->8].
template <int CTRL>
__device__ __forceinline__ float dpp_bfly_max(float x) {
  int xi = __builtin_bit_cast(int, x);
  int yi = __builtin_amdgcn_update_dpp(xi, xi, CTRL, 0xF, 0xF, false);
  return fmaxf(x, __builtin_bit_cast(float, yi));
}
template <int CTRL>
__device__ __forceinline__ float dpp_bfly_add(float x) {
  int xi = __builtin_bit_cast(int, x);
  int yi = __builtin_amdgcn_update_dpp(xi, xi, CTRL, 0xF, 0xF, false);
  return x + __builtin_bit_cast(float, yi);
}

// ---------------------------------------------------------------------------
// Elementwise fp32 -> bf16, 8 elems/thread, fully coalesced.
__global__ void conv_bf16(const float* __restrict__ src, bf16* __restrict__ dst) {
  size_t i = ((size_t)blockIdx.x * 256 + threadIdx.x) * 8;
  f32x4 a0 = *(const f32x4*)(src + i);
  f32x4 a1 = *(const f32x4*)(src + i + 4);
  *(bf16x8*)(dst + i) = pack8(a0, a1);
}

// ---------------------------------------------------------------------------
// Transpose+convert fp32 (R x C) -> bf16 (C x R). perm=1: qkv column remap
// col = which*2048 + d*16 + h  ->  which*2048 + h*128 + d  (dst-row permute).
__global__ void transpose_conv(const float* __restrict__ src, bf16* __restrict__ dst,
                               int R, int C, int perm) {
  __shared__ float tile[32][33];
  int bx = blockIdx.x * 32, by = blockIdx.y * 32;
  int tx = threadIdx.x, ty = threadIdx.y;
  for (int i = ty; i < 32; i += 8) tile[i][tx] = src[(size_t)(by + i) * C + bx + tx];
  __syncthreads();
  for (int i = ty; i < 32; i += 8) {
    int c = bx + i;
    if (perm) {
      int cc = c & 2047;
      c = (c & ~2047) | (((cc & 15) << 7) | (cc >> 4));
    }
    dst[(size_t)c * R + by + tx] = f2b(tile[tx][i]);
  }
}

// ---------------------------------------------------------------------------
// QKV GEMM: C(8192,6144) = xb(8192,2048) * WqkvT(6144,2048)^T. 128x128, BK=64.
// Columns permuted (d-fast). Per n-tile: one (which,h), full d in [0,128).
__global__ __launch_bounds__(256) void gemm_qkv(const bf16* __restrict__ A,
                                                const bf16* __restrict__ Bt,
                                                const float* __restrict__ biasf,
                                                bf16* __restrict__ Qg, bf16* __restrict__ Kg,
                                                bf16* __restrict__ Vg) {
  __shared__ alignas(16) bf16 smem[2 * 128 * 64];  // As | Bs; reused as [128][128] for V restage
  bf16* As = smem;
  bf16* Bs = smem + 128 * 64;
  const int K_ = 2048;
  int tid = threadIdx.x, lane = tid & 63, w = tid >> 6;
  int lr = lane & 15, hi = lane >> 4;
  int wm = (w >> 1) * 64, wn = (w & 1) * 64;
  int m0 = blockIdx.y * 128, n0 = blockIdx.x * 128;
  f32x4 acc[4][4];
#pragma unroll
  for (int im = 0; im < 4; ++im)
#pragma unroll
    for (int in = 0; in < 4; ++in) acc[im][in] = (f32x4){0.f, 0.f, 0.f, 0.f};

  for (int k0 = 0; k0 < K_; k0 += 64) {
    __syncthreads();
#pragma unroll
    for (int i = 0; i < 4; ++i) {
      int c = tid + 256 * i;
      int r = c >> 3, j = c & 7, jg = j ^ (r & 7);
      ASYNC16((char*)As + c * 16, (const char*)(A + (size_t)(m0 + r) * K_ + k0 + jg * 8));
    }
#pragma unroll
    for (int i = 0; i < 4; ++i) {
      int c = tid + 256 * i;
      int r = c >> 3, j = c & 7, jg = j ^ (r & 7);
      ASYNC16((char*)Bs + c * 16, (const char*)(Bt + (size_t)(n0 + r) * K_ + k0 + jg * 8));
    }
    __syncthreads();

#pragma unroll
    for (int ks = 0; ks < 2; ++ks) {
      bf16x8 afr[4], bfr[4];
#pragma unroll
      for (int im = 0; im < 4; ++im) {
        int r = wm + 16 * im + lr;
        afr[im] = *(const bf16x8*)((const char*)As + r * 128 + (((ks * 4 + hi) ^ (r & 7)) * 16));
      }
#pragma unroll
      for (int in = 0; in < 4; ++in) {
        int r = wn + 16 * in + lr;
        bfr[in] = *(const bf16x8*)((const char*)Bs + r * 128 + (((ks * 4 + hi) ^ (r & 7)) * 16));
      }
#pragma unroll
      for (int im = 0; im < 4; ++im)
#pragma unroll
        for (int in = 0; in < 4; ++in)
          acc[im][in] =
              __builtin_amdgcn_mfma_f32_16x16x32_bf16(afr[im], bfr[in], acc[im][in], 0, 0, 0);
    }
  }

  // Epilogue. Block-uniform: which, h. d = wn + 16*in + lr (full [0,128) per tile).
  int which = n0 >> 11;
  int h = (n0 >> 7) & 15;
  int bq = m0 >> 11;
  int l_base = m0 & 2047;
  int bh = bq * 16 + h;
  float bv[4];
#pragma unroll
  for (int in = 0; in < 4; ++in)
    bv[in] = biasf[(which << 11) + ((wn + 16 * in + lr) << 4) + h];

  if (which < 2) {
    bf16* __restrict__ G = (which == 0) ? Qg : Kg;
#pragma unroll
    for (int im = 0; im < 4; ++im) {
#pragma unroll
      for (int in = 0; in < 4; ++in) {
        int d = wn + 16 * in + lr;
#pragma unroll
        for (int j = 0; j < 4; ++j) {
          int l = l_base + wm + 16 * im + 4 * hi + j;
          G[((size_t)bh * 2048 + l) * 128 + d] = f2b(acc[im][in][j] + bv[in]);
        }
      }
    }
  } else {
    // V: restage [128 d][128 l] through LDS (XOR'd 8-elem l-chunks), 16B stores.
    __syncthreads();
#pragma unroll
    for (int im = 0; im < 4; ++im)
#pragma unroll
      for (int in = 0; in < 4; ++in) {
        int d = wn + 16 * in + lr;
#pragma unroll
        for (int j = 0; j < 4; ++j) {
          int l = wm + 16 * im + 4 * hi + j;
          int slot = (l >> 3) ^ (d & 15);
          smem[d * 128 + slot * 8 + (l & 7)] = f2b(acc[im][in][j] + bv[in]);
        }
      }
    __syncthreads();
#pragma unroll
    for (int s = 0; s < 8; ++s) {
      int d = (tid >> 4) + 16 * s;
      int lc = tid & 15;
      int slot = lc ^ (d & 15);
      bf16x8 v = *(const bf16x8*)(smem + d * 128 + slot * 8);
      *(bf16x8*)(Vg + ((size_t)bh * 128 + d) * 2048 + l_base + lc * 8) = v;
    }
  }
}

// ---------------------------------------------------------------------------
// FC2 GEMM: Out(8192,2048) = Y(8192,2048) * Wfc2T(2048,2048)^T, bias+SiLU, fp32 out.
__global__ __launch_bounds__(256) void gemm_fc2(const bf16* __restrict__ A,
                                                const bf16* __restrict__ Bt,
                                                const float* __restrict__ biasf,
                                                float* __restrict__ Out) {
  __shared__ alignas(16) bf16 As[128 * 64];
  __shared__ alignas(16) bf16 Bs[128 * 64];
  const int K_ = 2048;
  int tid = threadIdx.x, lane = tid & 63, w = tid >> 6;
  int lr = lane & 15, hi = lane >> 4;
  int wm = (w >> 1) * 64, wn = (w & 1) * 64;
  int m0 = blockIdx.y * 128, n0 = blockIdx.x * 128;
  f32x4 acc[4][4];
#pragma unroll
  for (int im = 0; im < 4; ++im)
#pragma unroll
    for (int in = 0; in < 4; ++in) acc[im][in] = (f32x4){0.f, 0.f, 0.f, 0.f};

  for (int k0 = 0; k0 < K_; k0 += 64) {
    __syncthreads();
#pragma unroll
    for (int i = 0; i < 4; ++i) {
      int c = tid + 256 * i;
      int r = c >> 3, j = c & 7, jg = j ^ (r & 7);
      ASYNC16((char*)As + c * 16, (const char*)(A + (size_t)(m0 + r) * K_ + k0 + jg * 8));
    }
#pragma unroll
    for (int i = 0; i < 4; ++i) {
      int c = tid + 256 * i;
      int r = c >> 3, j = c & 7, jg = j ^ (r & 7);
      ASYNC16((char*)Bs + c * 16, (const char*)(Bt + (size_t)(n0 + r) * K_ + k0 + jg * 8));
    }
    __syncthreads();
#pragma unroll
    for (int ks = 0; ks < 2; ++ks) {
      bf16x8 afr[4], bfr[4];
#pragma unroll
      for (int im = 0; im < 4; ++im) {
        int r = wm + 16 * im + lr;
        afr[im] = *(const bf16x8*)((const char*)As + r * 128 + (((ks * 4 + hi) ^ (r & 7)) * 16));
      }
#pragma unroll
      for (int in = 0; in < 4; ++in) {
        int r = wn + 16 * in + lr;
        bfr[in] = *(const bf16x8*)((const char*)Bs + r * 128 + (((ks * 4 + hi) ^ (r & 7)) * 16));
      }
#pragma unroll
      for (int im = 0; im < 4; ++im)
#pragma unroll
        for (int in = 0; in < 4; ++in)
          acc[im][in] =
              __builtin_amdgcn_mfma_f32_16x16x32_bf16(afr[im], bfr[in], acc[im][in], 0, 0, 0);
    }
  }

#pragma unroll
  for (int im = 0; im < 4; ++im) {
#pragma unroll
    for (int in = 0; in < 4; ++in) {
      int c = n0 + wn + 16 * in + lr;
      float bv = biasf[c];
#pragma unroll
      for (int j = 0; j < 4; ++j) {
        int m = m0 + wm + 16 * im + 4 * hi + j;
        float z = acc[im][in][j] + bv;
        Out[(size_t)m * 2048 + c] = z / (1.f + __expf(-z));
      }
    }
  }
}

// ---------------------------------------------------------------------------
// Rotary in-place on Q,K head layout. Pair (d, d+64), angle col = d*16+h. fp32 cos/sin.
__global__ void rotary_kernel(bf16* __restrict__ Qg, bf16* __restrict__ Kg,
                              const float* __restrict__ cosp, const float* __restrict__ sinp) {
  int idx = blockIdx.x * 256 + threadIdx.x;  // B*NH*L*64 = 8388608
  int d = idx & 63;
  int l = (idx >> 6) & 2047;
  int bh = idx >> 17;
  int h = bh & 15;
  size_t base = ((size_t)bh * 2048 + l) * 128;
  int ang = l * 1024 + d * 16 + h;
  float c = cosp[ang], s = sinp[ang];
  float q1 = b2f(Qg[base + d]), q2 = b2f(Qg[base + d + 64]);
  Qg[base + d] = f2b(q1 * c + q2 * s);
  Qg[base + d + 64] = f2b(-q1 * s + q2 * c);
  float k1 = b2f(Kg[base + d]), k2 = b2f(Kg[base + d + 64]);
  Kg[base + d] = f2b(k1 * c + k2 * s);
  Kg[base + d + 64] = f2b(-k1 * s + k2 * c);
}

// ---------------------------------------------------------------------------
// Causal flash attention. Round 15: 512 threads / 8 waves, QBLK=128, 16 q-rows
// per wave (round-13 per-wave shape). One K/V staging serves 8 waves; per-wave
// uniform causal skip; elementwise mask only on boundary tiles.
__global__ __launch_bounds__(512) void flash_kernel(const bf16* __restrict__ Qg,
                                                    const bf16* __restrict__ Kg,
                                                    const bf16* __restrict__ Vg,
                                                    bf16* __restrict__ Y) {
  __shared__ alignas(16) bf16 Ks[64 * 128];
  __shared__ alignas(16) bf16 Vt[128 * 64];
  __shared__ alignas(16) bf16 Ps[8 * 16 * 72];  // 18 KB, wave-private regions
  int tid = threadIdx.x, lane = tid & 63, w = tid >> 6;  // w in [0,8)
  int lr = lane & 15, hi = lane >> 4;
  int it = 15 - (int)blockIdx.x;
  int bh = blockIdx.y;
  int b = bh >> 4, h = bh & 15;
  int q0 = it * 128;
  int qb = q0 + 16 * w;  // wave's first q-row
  const bf16* Qb = Qg + (size_t)bh * 2048 * 128;
  const bf16* Kb = Kg + (size_t)bh * 2048 * 128;
  const bf16* Vb = Vg + (size_t)bh * 128 * 2048;
  const float NEG = -1.0e30f;

  // Q fragments straight to registers (constant across jt; wave-private rows).
  bf16x8 qf[4];
#pragma unroll
  for (int ks = 0; ks < 4; ++ks)
    qf[ks] = *(const bf16x8*)(Qb + (size_t)(qb + lr) * 128 + (ks * 4 + hi) * 8);

  // Prologue: issue K/V loads for jt=0 into staging registers (2 chunks each).
  bf16x8 kreg[2], vreg[2];
#pragma unroll
  for (int i = 0; i < 2; ++i) {
    int c = tid + 512 * i;
    int rk = c >> 4, jk = (c & 15) ^ (rk & 7);
    kreg[i] = *(const bf16x8*)(Kb + (size_t)rk * 128 + jk * 8);
    int rv = c >> 3, jv = (c & 7) ^ (rv & 7);
    vreg[i] = *(const bf16x8*)(Vb + (size_t)rv * 2048 + jv * 8);
  }

  f32x4 o[8];
#pragma unroll
  for (int i = 0; i < 8; ++i) o[i] = (f32x4){0.f, 0.f, 0.f, 0.f};
  float m_i[4], l_i[4];
#pragma unroll
  for (int j = 0; j < 4; ++j) { m_i[j] = NEG; l_i[j] = 0.f; }
  const float scale = 0.08838834764831845f;  // 1/sqrt(128)

  int jt_max = 2 * it + 1;
  for (int jt = 0; jt <= jt_max; ++jt) {
    int k0 = jt * 64;
    __syncthreads();  // all waves done reading Ks/Vt of previous tile
#pragma unroll
    for (int i = 0; i < 2; ++i) {
      int c = tid + 512 * i;
      *(bf16x8*)((char*)Ks + c * 16) = kreg[i];
      *(bf16x8*)((char*)Vt + c * 16) = vreg[i];
    }
    __syncthreads();  // staged tile visible to all waves

    // T14: issue next tile's global loads now; consumed at next iter's ds_write.
    if (jt < jt_max) {
      int k0n = k0 + 64;
#pragma unroll
      for (int i = 0; i < 2; ++i) {
        int c = tid + 512 * i;
        int rk = c >> 4, jk = (c & 15) ^ (rk & 7);
        kreg[i] = *(const bf16x8*)(Kb + (size_t)(k0n + rk) * 128 + jk * 8);
        int rv = c >> 3, jv = (c & 7) ^ (rv & 7);
        vreg[i] = *(const bf16x8*)(Vb + (size_t)rv * 2048 + k0n + jv * 8);
      }
    }

    // Wave-uniform causal skip: all k in tile beyond all of this wave's q-rows.
    if (k0 > qb + 15) continue;  // wave-coherent; barriers are above

    f32x4 sacc[4];
#pragma unroll
    for (int in = 0; in < 4; ++in) sacc[in] = (f32x4){0.f, 0.f, 0.f, 0.f};
#pragma unroll
    for (int ks = 0; ks < 4; ++ks) {
#pragma unroll
      for (int in = 0; in < 4; ++in) {
        int br = 16 * in + lr;
        bf16x8 bb =
            *(const bf16x8*)((const char*)Ks + br * 256 + (((ks * 4 + hi) ^ (br & 7)) * 16));
        sacc[in] = __builtin_amdgcn_mfma_f32_16x16x32_bf16(qf[ks], bb, sacc[in], 0, 0, 0);
      }
    }

    // Softmax: register max + DPP butterflies (4 independent j-chains batched).
    bool needmask = (k0 + 63 > qb);  // some k could exceed some q
    float mxr[4], alpha[4], rsum[4];
#pragma unroll
    for (int j = 0; j < 4; ++j) {
      float mx = NEG;
#pragma unroll
      for (int in = 0; in < 4; ++in) {
        float s = sacc[in][j] * scale;
        if (needmask) {
          int qg_ = qb + 4 * hi + j;
          int kg_ = k0 + 16 * in + lr;
          if (kg_ > qg_) s = NEG;
        }
        sacc[in][j] = s;
        mx = fmaxf(mx, s);
      }
      mxr[j] = mx;
    }
#pragma unroll
    for (int j = 0; j < 4; ++j) mxr[j] = dpp_bfly_max<0xB1>(mxr[j]);
#pragma unroll
    for (int j = 0; j < 4; ++j) mxr[j] = dpp_bfly_max<0x4E>(mxr[j]);
#pragma unroll
    for (int j = 0; j < 4; ++j) mxr[j] = dpp_bfly_max<0x141>(mxr[j]);
#pragma unroll
    for (int j = 0; j < 4; ++j) mxr[j] = dpp_bfly_max<0x140>(mxr[j]);

#pragma unroll
    for (int j = 0; j < 4; ++j) {
      float mnew = fmaxf(m_i[j], mxr[j]);
      alpha[j] = __expf(m_i[j] - mnew);
      m_i[j] = mnew;
      float r = 0.f;
#pragma unroll
      for (int in = 0; in < 4; ++in) {
        float p = __expf(sacc[in][j] - mnew);
        sacc[in][j] = p;
        r += p;
      }
      rsum[j] = r;
    }
#pragma unroll
    for (int j = 0; j < 4; ++j) rsum[j] = dpp_bfly_add<0xB1>(rsum[j]);
#pragma unroll
    for (int j = 0; j < 4; ++j) rsum[j] = dpp_bfly_add<0x4E>(rsum[j]);
#pragma unroll
    for (int j = 0; j < 4; ++j) rsum[j] = dpp_bfly_add<0x141>(rsum[j]);
#pragma unroll
    for (int j = 0; j < 4; ++j) rsum[j] = dpp_bfly_add<0x140>(rsum[j]);

#pragma unroll
    for (int j = 0; j < 4; ++j) {
      l_i[j] = alpha[j] * l_i[j] + rsum[j];
#pragma unroll
      for (int inp = 0; inp < 8; ++inp) o[inp][j] *= alpha[j];
    }

#pragma unroll
    for (int j = 0; j < 4; ++j)
#pragma unroll
      for (int in = 0; in < 4; ++in)
        Ps[w * 1152 + (4 * hi + j) * 72 + 16 * in + lr] = f2b(sacc[in][j]);
    // Ps region is wave-private (w-indexed); only need this wave's LDS ops done.
    asm volatile("s_waitcnt lgkmcnt(0)" ::: "memory");

#pragma unroll
    for (int ko = 0; ko < 2; ++ko) {
      bf16x8 a = *(const bf16x8*)((const char*)Ps + (w * 1152 + lr * 72 + ko * 32 + hi * 8) * 2);
#pragma unroll
      for (int inp = 0; inp < 8; ++inp) {
        int br = 16 * inp + lr;
        bf16x8 bb =
            *(const bf16x8*)((const char*)Vt + br * 128 + (((ko * 4 + hi) ^ (br & 7)) * 16));
        o[inp] = __builtin_amdgcn_mfma_f32_16x16x32_bf16(a, bb, o[inp], 0, 0, 0);
      }
    }
  }

#pragma unroll
  for (int j = 0; j < 4; ++j) {
    int qg_ = qb + 4 * hi + j;
    float inv = 1.f / l_i[j];
    size_t rowb = ((size_t)(b * 2048 + qg_)) * 2048 + h * 128;
#pragma unroll
    for (int inp = 0; inp < 8; ++inp) {
      int dd = 16 * inp + lr;
      Y[rowb + dd] = f2b(o[inp][j] * inv);
    }
  }
}

// ---------------------------------------------------------------------------
extern "C" void kernel_launch(void* const* d_in, const int* in_sizes, int n_in,
                              void* d_out, int out_size, void* d_ws, size_t ws_size,
                              hipStream_t stream) {
  const float* x    = (const float*)d_in[0];  // 8192 x 2048
  const float* Wqkv = (const float*)d_in[1];  // 2048 x 6144
  const float* bqkv = (const float*)d_in[2];  // 6144
  const float* Wfc2 = (const float*)d_in[3];  // 2048 x 2048
  const float* bfc2 = (const float*)d_in[4];  // 2048
  const float* cosp = (const float*)d_in[5];  // 2048 x 1024
  const float* sinp = (const float*)d_in[6];  // 2048 x 1024
  float* out = (float*)d_out;

  // Workspace (bf16 elems), exactly 67,108,864 = 128 MB:
  //   [0, 16.78M):      Yg (flash out). WqkvT [0,12.58M) aliased pre-flash.
  //   [16.78M, 33.55M): Qg. Wfc2T [+0,+4.19M) aliased post-flash.
  //   [33.55M, 50.33M): Kg.
  //   [50.33M, 67.11M): Vg [bh][128][l].
  // x_bf16 (16.78M elems = 33.5 MB) parked in d_out (67 MB fp32, dead until fc2).
  bf16* ws = (bf16*)d_ws;
  bf16* Yg    = ws;
  bf16* WqkvT = ws;
  bf16* Qg    = ws + 16777216;
  bf16* Wfc2T = ws + 16777216;
  bf16* Kg    = ws + 33554432;
  bf16* Vg    = ws + 50331648;
  bf16* xb    = (bf16*)d_out;

  conv_bf16<<<8192, 256, 0, stream>>>(x, xb);
  transpose_conv<<<dim3(192, 64), dim3(32, 8), 0, stream>>>(Wqkv, WqkvT, 2048, 6144, 1);
  gemm_qkv<<<dim3(48, 64), 256, 0, stream>>>(xb, WqkvT, bqkv, Qg, Kg, Vg);
  rotary_kernel<<<32768, 256, 0, stream>>>(Qg, Kg, cosp, sinp);
  flash_kernel<<<dim3(16, 64), 512, 0, stream>>>(Qg, Kg, Vg, Yg);
  transpose_conv<<<dim3(64, 64), dim3(32, 8), 0, stream>>>(Wfc2, Wfc2T, 2048, 2048, 0);
  gemm_fc2<<<dim3(16, 64), 256, 0, stream>>>(Yg, Wfc2T, bfc2, out);
}